// Round 1
// baseline (918.832 us; speedup 1.0000x reference)
//
#include <hip/hip_runtime.h>
#include <math.h>

#define N_NODES 50000
#define N_EDGES 800000
#define ET (N_EDGES + N_NODES)

// ---------------- CSR build ----------------

__global__ void k_init_deg(int* deg, int n) {
    int i = blockIdx.x * blockDim.x + threadIdx.x;
    if (i < n) deg[i] = 1;  // self-loop pre-counted
}

__global__ void k_count(const int* __restrict__ dst, int* __restrict__ deg, int e) {
    int i = blockIdx.x * blockDim.x + threadIdx.x;
    if (i < e) atomicAdd(&deg[dst[i]], 1);
}

// single-block exclusive scan over n values (n <= ~64k fine); writes rowptr[0..n] and cursor[0..n)
__global__ void k_scan(const int* __restrict__ deg, int* __restrict__ rowptr,
                       int* __restrict__ cursor, int n) {
    __shared__ int sh[1024];
    __shared__ int carry_sh;
    if (threadIdx.x == 0) carry_sh = 0;
    __syncthreads();
    for (int base = 0; base < n; base += 1024) {
        int i = base + threadIdx.x;
        int v = (i < n) ? deg[i] : 0;
        sh[threadIdx.x] = v;
        __syncthreads();
        for (int off = 1; off < 1024; off <<= 1) {
            int t = 0;
            if ((int)threadIdx.x >= off) t = sh[threadIdx.x - off];
            __syncthreads();
            sh[threadIdx.x] += t;
            __syncthreads();
        }
        int incl = sh[threadIdx.x];
        int carry = carry_sh;
        if (i < n) {
            rowptr[i] = carry + incl - v;
            cursor[i] = carry + incl - v;
        }
        __syncthreads();
        if (threadIdx.x == 1023) carry_sh = carry + incl;
        __syncthreads();
    }
    if (threadIdx.x == 0) rowptr[n] = carry_sh;
}

__global__ void k_fill(const int* __restrict__ src, const int* __restrict__ dst,
                       int* __restrict__ cursor, int* __restrict__ csr_src) {
    int i = blockIdx.x * blockDim.x + threadIdx.x;
    if (i < N_EDGES) {
        int d = dst[i];
        int pos = atomicAdd(&cursor[d], 1);
        csr_src[pos] = src[i];
    } else if (i < ET) {
        int node = i - N_EDGES;
        int pos = atomicAdd(&cursor[node], 1);
        csr_src[pos] = node;
    }
}

// ---------------- node GEMM: xl = x@Wl + bl, xr = x@Wr + br ----------------
// one block per node, block = 2*HD threads (first half -> xl, second -> xr)

template<int DIN, int HD>
__global__ void k_gemm(const float* __restrict__ x,
                       const float* __restrict__ Wl, const float* __restrict__ bl,
                       const float* __restrict__ Wr, const float* __restrict__ br,
                       float* __restrict__ xl, float* __restrict__ xr) {
    __shared__ float xs[DIN];
    int node = blockIdx.x;
    int t = threadIdx.x;
    for (int k = t; k < DIN; k += 2 * HD) xs[k] = x[node * DIN + k];
    __syncthreads();
    const float* W = (t < HD) ? Wl : Wr;
    const float* b = (t < HD) ? bl : br;
    float* o       = (t < HD) ? xl : xr;
    int oc         = (t < HD) ? t : t - HD;
    float acc = b[oc];
#pragma unroll
    for (int k = 0; k < DIN; k++) acc = fmaf(xs[k], W[k * HD + oc], acc);
    o[node * HD + oc] = acc;
}

// ---------------- GATv2 edge gather with online softmax ----------------
// HD = heads*dout total dims, D = per-head dim, VEC dims per lane.
// L = HD/VEC lanes per node; NPW = 64/L nodes per wave.

template<int HD, int D, int VEC>
__global__ void k_gather(const float* __restrict__ xl, const float* __restrict__ xr,
                         const float* __restrict__ att,
                         const int* __restrict__ rowptr, const int* __restrict__ csr_src,
                         float* __restrict__ out, int n) {
    constexpr int L = HD / VEC;
    constexpr int NPW = 64 / L;
    int tid = blockIdx.x * blockDim.x + threadIdx.x;
    int wave = tid / 64;
    int lane = tid & 63;
    int node = wave * NPW + lane / L;
    if (node >= n) return;
    int sub = lane % L;
    int f = sub * VEC;
    float xrv[VEC], attv[VEC], acc[VEC];
#pragma unroll
    for (int i = 0; i < VEC; i++) {
        xrv[i]  = xr[node * HD + f + i];
        attv[i] = att[f + i];
        acc[i]  = 0.f;
    }
    float m = -INFINITY, denom = 0.f;
    int e0 = rowptr[node], e1 = rowptr[node + 1];
    for (int j = e0; j < e1; j++) {
        int s = csr_src[j];
        float xlv[VEC];
        float part = 0.f;
#pragma unroll
        for (int i = 0; i < VEC; i++) {
            xlv[i] = xl[s * HD + f + i];
            float e = xlv[i] + xrv[i];
            e = (e > 0.f) ? e : 0.2f * e;
            part = fmaf(e, attv[i], part);
        }
        constexpr int G = D / VEC;  // lanes per head group (power of 2, group-aligned)
#pragma unroll
        for (int msk = G / 2; msk >= 1; msk >>= 1) part += __shfl_xor(part, msk, 64);
        float nm = fmaxf(m, part);
        float sc = __expf(m - nm);        // m=-inf first iter -> 0
        float w  = __expf(part - nm);
        denom = fmaf(denom, sc, w);
#pragma unroll
        for (int i = 0; i < VEC; i++) acc[i] = fmaf(acc[i], sc, w * xlv[i]);
        m = nm;
    }
    float inv = 1.f / denom;
#pragma unroll
    for (int i = 0; i < VEC; i++) out[node * HD + f + i] = acc[i] * inv;
}

// ---------------- +bo, LayerNorm, ELU, optional residual ----------------

template<int LDIM, int VEC, bool RES>
__global__ void k_ln(const float* __restrict__ in, const float* __restrict__ bo,
                     const float* __restrict__ g, const float* __restrict__ be,
                     const float* res, float* outh, int n) {
    constexpr int L = LDIM / VEC;
    constexpr int NPW = 64 / L;
    int tid = blockIdx.x * blockDim.x + threadIdx.x;
    int wave = tid / 64;
    int lane = tid & 63;
    int node = wave * NPW + lane / L;
    if (node >= n) return;
    int sub = lane % L;
    int f = sub * VEC;
    float v[VEC];
    float s = 0.f;
#pragma unroll
    for (int i = 0; i < VEC; i++) {
        v[i] = in[node * LDIM + f + i] + bo[f + i];
        s += v[i];
    }
#pragma unroll
    for (int msk = L / 2; msk >= 1; msk >>= 1) s += __shfl_xor(s, msk, 64);
    float mu = s * (1.f / LDIM);
    float q = 0.f;
#pragma unroll
    for (int i = 0; i < VEC; i++) { float d = v[i] - mu; q += d * d; }
#pragma unroll
    for (int msk = L / 2; msk >= 1; msk >>= 1) q += __shfl_xor(q, msk, 64);
    float rstd = rsqrtf(q * (1.f / LDIM) + 1e-5f);
#pragma unroll
    for (int i = 0; i < VEC; i++) {
        float y = (v[i] - mu) * rstd * g[f + i] + be[f + i];
        y = (y > 0.f) ? y : expm1f(y);   // ELU
        if (RES) y += res[node * LDIM + f + i];
        outh[node * LDIM + f + i] = y;
    }
}

// ---------------- classifier head: ELU(h@cW1+cb1)@cW2+cb2 ----------------

__global__ void k_cls(const float* __restrict__ h,
                      const float* __restrict__ cW1, const float* __restrict__ cb1,
                      const float* __restrict__ cW2, const float* __restrict__ cb2,
                      float* __restrict__ out, int n) {
    __shared__ float w1[32 * 16];
    __shared__ float b1[16];
    __shared__ float w2[16];
    __shared__ float b2s;
    int t = threadIdx.x;
    for (int i = t; i < 512; i += blockDim.x) w1[i] = cW1[i];
    if (t < 16) { b1[t] = cb1[t]; w2[t] = cW2[t]; }
    if (t == 0) b2s = cb2[0];
    __syncthreads();
    int node = blockIdx.x * blockDim.x + t;
    if (node >= n) return;
    float hv[32];
#pragma unroll
    for (int k = 0; k < 32; k++) hv[k] = h[node * 32 + k];
    float o = b2s;
#pragma unroll
    for (int j = 0; j < 16; j++) {
        float a = b1[j];
#pragma unroll
        for (int k = 0; k < 32; k++) a = fmaf(hv[k], w1[k * 16 + j], a);
        a = (a > 0.f) ? a : expm1f(a);
        o = fmaf(a, w2[j], o);
    }
    out[node] = o;
}

// ---------------- launch ----------------

extern "C" void kernel_launch(void* const* d_in, const int* in_sizes, int n_in,
                              void* d_out, int out_size, void* d_ws, size_t ws_size,
                              hipStream_t stream) {
    (void)in_sizes; (void)n_in; (void)out_size; (void)ws_size;
    const float* x  = (const float*)d_in[0];
    const int*   ei = (const int*)d_in[1];
    const int* src = ei;
    const int* dst = ei + N_EDGES;

    const float* Wl0 = (const float*)d_in[2];
    const float* bl0 = (const float*)d_in[3];
    const float* Wr0 = (const float*)d_in[4];
    const float* br0 = (const float*)d_in[5];
    const float* att0= (const float*)d_in[6];
    const float* bo0 = (const float*)d_in[7];
    const float* g0  = (const float*)d_in[8];
    const float* be0 = (const float*)d_in[9];
    const float* Wl1 = (const float*)d_in[10];
    const float* bl1 = (const float*)d_in[11];
    const float* Wr1 = (const float*)d_in[12];
    const float* br1 = (const float*)d_in[13];
    const float* att1= (const float*)d_in[14];
    const float* bo1 = (const float*)d_in[15];
    const float* g1  = (const float*)d_in[16];
    const float* be1 = (const float*)d_in[17];
    const float* Wl2 = (const float*)d_in[18];
    const float* bl2 = (const float*)d_in[19];
    const float* Wr2 = (const float*)d_in[20];
    const float* br2 = (const float*)d_in[21];
    const float* att2= (const float*)d_in[22];
    const float* bo2 = (const float*)d_in[23];
    const float* g2  = (const float*)d_in[24];
    const float* be2 = (const float*)d_in[25];
    const float* cW1 = (const float*)d_in[26];
    const float* cb1 = (const float*)d_in[27];
    const float* cW2 = (const float*)d_in[28];
    const float* cb2 = (const float*)d_in[29];

    char* ws = (char*)d_ws;
    float* h  = (float*)ws; ws += (size_t)N_NODES * 128 * 4;
    float* xl = (float*)ws; ws += (size_t)N_NODES * 128 * 4;
    float* xr = (float*)ws; ws += (size_t)N_NODES * 128 * 4;
    float* o  = (float*)ws; ws += (size_t)N_NODES * 128 * 4;
    int* rowptr  = (int*)ws; ws += (size_t)(N_NODES + 1) * 4;
    int* cursor  = (int*)ws; ws += (size_t)N_NODES * 4;
    int* deg     = (int*)ws; ws += (size_t)N_NODES * 4;
    int* csr_src = (int*)ws; ws += (size_t)ET * 4;

    // ---- CSR build (dst -> incoming src list), once per launch ----
    k_init_deg<<<(N_NODES + 255) / 256, 256, 0, stream>>>(deg, N_NODES);
    k_count<<<(N_EDGES + 255) / 256, 256, 0, stream>>>(dst, deg, N_EDGES);
    k_scan<<<1, 1024, 0, stream>>>(deg, rowptr, cursor, N_NODES);
    k_fill<<<(ET + 255) / 256, 256, 0, stream>>>(src, dst, cursor, csr_src);

    const int grid64 = (N_NODES * 64 + 255) / 256;  // 1 wave per node
    const int grid32 = (N_NODES * 32 + 255) / 256;  // 2 nodes per wave

    // ---- layer 0: din=18 -> 4 heads x 32, concat -> 128 ----
    k_gemm<18, 128><<<N_NODES, 256, 0, stream>>>(x, Wl0, bl0, Wr0, br0, xl, xr);
    k_gather<128, 32, 2><<<grid64, 256, 0, stream>>>(xl, xr, att0, rowptr, csr_src, o, N_NODES);
    k_ln<128, 2, false><<<grid64, 256, 0, stream>>>(o, bo0, g0, be0, nullptr, h, N_NODES);

    // ---- layer 1: din=128 -> 4x32 concat -> 128, residual ----
    k_gemm<128, 128><<<N_NODES, 256, 0, stream>>>(h, Wl1, bl1, Wr1, br1, xl, xr);
    k_gather<128, 32, 2><<<grid64, 256, 0, stream>>>(xl, xr, att1, rowptr, csr_src, o, N_NODES);
    k_ln<128, 2, true><<<grid64, 256, 0, stream>>>(o, bo1, g1, be1, h, h, N_NODES);

    // ---- layer 2: din=128 -> 1x32, no concat ----
    k_gemm<128, 32><<<N_NODES, 64, 0, stream>>>(h, Wl2, bl2, Wr2, br2, xl, xr);
    k_gather<32, 32, 1><<<grid32, 256, 0, stream>>>(xl, xr, att2, rowptr, csr_src, o, N_NODES);
    k_ln<32, 1, false><<<grid32, 256, 0, stream>>>(o, bo2, g2, be2, nullptr, h, N_NODES);

    // ---- classifier ----
    k_cls<<<(N_NODES + 255) / 256, 256, 0, stream>>>(h, cW1, cb1, cW2, cb2, (float*)d_out, N_NODES);
}

// Round 3
// 784.759 us; speedup vs baseline: 1.1708x; 1.1708x over previous
//
#include <hip/hip_runtime.h>
#include <math.h>

#define N_NODES 50000
#define N_EDGES 800000
#define ET (N_EDGES + N_NODES)

// ---------------- CSR build ----------------

__global__ void k_init_deg(int* deg, int n) {
    int i = blockIdx.x * blockDim.x + threadIdx.x;
    if (i < n) deg[i] = 1;  // self-loop pre-counted
}

__global__ void k_count(const int* __restrict__ dst, int* __restrict__ deg, int e) {
    int i = blockIdx.x * blockDim.x + threadIdx.x;
    if (i < e) atomicAdd(&deg[dst[i]], 1);
}

// single-block exclusive scan; writes rowptr[0..n] and cursor[0..n)
__global__ void k_scan(const int* __restrict__ deg, int* __restrict__ rowptr,
                       int* __restrict__ cursor, int n) {
    __shared__ int sh[1024];
    __shared__ int carry_sh;
    if (threadIdx.x == 0) carry_sh = 0;
    __syncthreads();
    for (int base = 0; base < n; base += 1024) {
        int i = base + threadIdx.x;
        int v = (i < n) ? deg[i] : 0;
        sh[threadIdx.x] = v;
        __syncthreads();
        for (int off = 1; off < 1024; off <<= 1) {
            int t = 0;
            if ((int)threadIdx.x >= off) t = sh[threadIdx.x - off];
            __syncthreads();
            sh[threadIdx.x] += t;
            __syncthreads();
        }
        int incl = sh[threadIdx.x];
        int carry = carry_sh;
        if (i < n) {
            rowptr[i] = carry + incl - v;
            cursor[i] = carry + incl - v;
        }
        __syncthreads();
        if (threadIdx.x == 1023) carry_sh = carry + incl;
        __syncthreads();
    }
    if (threadIdx.x == 0) rowptr[n] = carry_sh;
}

__global__ void k_fill(const int* __restrict__ src, const int* __restrict__ dst,
                       int* __restrict__ cursor, int* __restrict__ csr_src) {
    int i = blockIdx.x * blockDim.x + threadIdx.x;
    if (i < N_EDGES) {
        int d = dst[i];
        int pos = atomicAdd(&cursor[d], 1);
        csr_src[pos] = src[i];
    } else if (i < ET) {
        int node = i - N_EDGES;
        int pos = atomicAdd(&cursor[node], 1);
        csr_src[pos] = node;
    }
}

// ---------------- tiled node GEMM: xl = x@Wl + bl, xr = x@Wr + br ----------------
// BM=64 nodes per block, BN output cols per block. grid.y picks (Wl/Wr, col tile).
// 256 threads; each thread computes a 4 x (BN/16) microtile from LDS.

template<int K, int HD, int BN>
__global__ void k_gemm_t(const float* __restrict__ x,
                         const float* __restrict__ Wl, const float* __restrict__ bl,
                         const float* __restrict__ Wr, const float* __restrict__ br,
                         float* __restrict__ xl, float* __restrict__ xr, int n) {
    constexpr int BM = 64;
    constexpr int TM = 4;
    constexpr int TN = BN / 16;
    constexpr int CT_PER = HD / BN;  // column tiles per weight matrix
    __shared__ float xs[BM][K + 1];
    __shared__ float ws[K][BN + 4];
    int m0 = blockIdx.x * BM;
    int ct = blockIdx.y;
    const float* W = (ct < CT_PER) ? Wl : Wr;
    const float* bias = (ct < CT_PER) ? bl : br;
    float* o = (ct < CT_PER) ? xl : xr;
    int colBase = (ct % CT_PER) * BN;
    int t = threadIdx.x;
    for (int i = t; i < BM * K; i += 256) {
        int r = i / K, c = i % K;
        xs[r][c] = (m0 + r < n) ? x[(size_t)(m0 + r) * K + c] : 0.f;
    }
    for (int i = t; i < K * BN; i += 256) {
        int r = i / BN, c = i % BN;
        ws[r][c] = W[r * HD + colBase + c];
    }
    __syncthreads();
    int tr = t / 16, tc = t % 16;
    float acc[TM][TN];
#pragma unroll
    for (int j = 0; j < TN; j++) {
        float bv = bias[colBase + tc * TN + j];
#pragma unroll
        for (int i = 0; i < TM; i++) acc[i][j] = bv;
    }
#pragma unroll 4
    for (int k = 0; k < K; k++) {
        float a[TM];
#pragma unroll
        for (int i = 0; i < TM; i++) a[i] = xs[tr * TM + i][k];
#pragma unroll
        for (int j = 0; j < TN; j++) {
            float bb = ws[k][tc * TN + j];
#pragma unroll
            for (int i = 0; i < TM; i++) acc[i][j] = fmaf(a[i], bb, acc[i][j]);
        }
    }
#pragma unroll
    for (int i = 0; i < TM; i++) {
        int r = m0 + tr * TM + i;
        if (r < n) {
#pragma unroll
            for (int j = 0; j < TN; j++)
                o[(size_t)r * HD + colBase + tc * TN + j] = acc[i][j];
        }
    }
}

// ---------------- fused GATv2 gather + online softmax + bias + LN + ELU (+res) ----
// HD dims total, D per-head, VEC dims per lane. L=HD/VEC lanes per node.

template<int HD, int D, int VEC, bool RES>
__global__ void k_gather_ln(const float* __restrict__ xl, const float* __restrict__ xr,
                            const float* __restrict__ att,
                            const int* __restrict__ rowptr, const int* __restrict__ csr_src,
                            const float* __restrict__ bo, const float* __restrict__ g,
                            const float* __restrict__ be, const float* res,
                            float* __restrict__ outh, int n) {
    constexpr int L = HD / VEC;
    constexpr int NPW = 64 / L;
    int tid = blockIdx.x * blockDim.x + threadIdx.x;
    int wave = tid / 64;
    int lane = tid & 63;
    int node = wave * NPW + lane / L;
    if (node >= n) return;
    int sub = lane % L;
    int f = sub * VEC;
    float xrv[VEC], attv[VEC], acc[VEC];
#pragma unroll
    for (int i = 0; i < VEC; i++) {
        xrv[i]  = xr[(size_t)node * HD + f + i];
        attv[i] = att[f + i];
        acc[i]  = 0.f;
    }
    float m = -INFINITY, denom = 0.f;
    int e0 = rowptr[node], e1 = rowptr[node + 1];
    for (int j = e0; j < e1; j++) {
        int s = csr_src[j];
        float xlv[VEC];
        if constexpr (VEC == 2) {
            float2 tv = ((const float2*)(xl + (size_t)s * HD))[sub];
            xlv[0] = tv.x; xlv[1] = tv.y;
        } else {
            xlv[0] = xl[(size_t)s * HD + f];
        }
        float part = 0.f;
#pragma unroll
        for (int i = 0; i < VEC; i++) {
            float e = xlv[i] + xrv[i];
            e = (e > 0.f) ? e : 0.2f * e;
            part = fmaf(e, attv[i], part);
        }
        constexpr int G = D / VEC;  // lanes per head
#pragma unroll
        for (int msk = G / 2; msk >= 1; msk >>= 1) part += __shfl_xor(part, msk, 64);
        float nm = fmaxf(m, part);
        float sc = __expf(m - nm);
        float w  = __expf(part - nm);
        denom = fmaf(denom, sc, w);
#pragma unroll
        for (int i = 0; i < VEC; i++) acc[i] = fmaf(acc[i], sc, w * xlv[i]);
        m = nm;
    }
    float inv = 1.f / denom;
    // ---- fused +bo, LayerNorm over HD dims (L lanes), ELU, residual ----
    float v[VEC];
    float s = 0.f;
#pragma unroll
    for (int i = 0; i < VEC; i++) {
        v[i] = acc[i] * inv + bo[f + i];
        s += v[i];
    }
#pragma unroll
    for (int msk = L / 2; msk >= 1; msk >>= 1) s += __shfl_xor(s, msk, 64);
    float mu = s * (1.f / HD);
    float q = 0.f;
#pragma unroll
    for (int i = 0; i < VEC; i++) { float d = v[i] - mu; q += d * d; }
#pragma unroll
    for (int msk = L / 2; msk >= 1; msk >>= 1) q += __shfl_xor(q, msk, 64);
    float rstd = rsqrtf(q * (1.f / HD) + 1e-5f);
#pragma unroll
    for (int i = 0; i < VEC; i++) {
        float y = (v[i] - mu) * rstd * g[f + i] + be[f + i];
        y = (y > 0.f) ? y : expm1f(y);
        if (RES) y += res[(size_t)node * HD + f + i];
        outh[(size_t)node * HD + f + i] = y;
    }
}

// ---------------- classifier head ----------------

__global__ void k_cls(const float* __restrict__ h,
                      const float* __restrict__ cW1, const float* __restrict__ cb1,
                      const float* __restrict__ cW2, const float* __restrict__ cb2,
                      float* __restrict__ out, int n) {
    __shared__ float w1[32 * 16];
    __shared__ float b1[16];
    __shared__ float w2[16];
    __shared__ float b2s;
    int t = threadIdx.x;
    for (int i = t; i < 512; i += blockDim.x) w1[i] = cW1[i];
    if (t < 16) { b1[t] = cb1[t]; w2[t] = cW2[t]; }
    if (t == 0) b2s = cb2[0];
    __syncthreads();
    int node = blockIdx.x * blockDim.x + t;
    if (node >= n) return;
    float hv[32];
#pragma unroll
    for (int k = 0; k < 32; k++) hv[k] = h[(size_t)node * 32 + k];
    float o = b2s;
#pragma unroll
    for (int j = 0; j < 16; j++) {
        float a = b1[j];
#pragma unroll
        for (int k = 0; k < 32; k++) a = fmaf(hv[k], w1[k * 16 + j], a);
        a = (a > 0.f) ? a : expm1f(a);
        o = fmaf(a, w2[j], o);
    }
    out[node] = o;
}

// ---------------- launch ----------------

extern "C" void kernel_launch(void* const* d_in, const int* in_sizes, int n_in,
                              void* d_out, int out_size, void* d_ws, size_t ws_size,
                              hipStream_t stream) {
    (void)in_sizes; (void)n_in; (void)out_size; (void)ws_size;
    const float* x  = (const float*)d_in[0];
    const int*   ei = (const int*)d_in[1];
    const int* src = ei;
    const int* dst = ei + N_EDGES;

    const float* Wl0 = (const float*)d_in[2];
    const float* bl0 = (const float*)d_in[3];
    const float* Wr0 = (const float*)d_in[4];
    const float* br0 = (const float*)d_in[5];
    const float* att0= (const float*)d_in[6];
    const float* bo0 = (const float*)d_in[7];
    const float* g0  = (const float*)d_in[8];
    const float* be0 = (const float*)d_in[9];
    const float* Wl1 = (const float*)d_in[10];
    const float* bl1 = (const float*)d_in[11];
    const float* Wr1 = (const float*)d_in[12];
    const float* br1 = (const float*)d_in[13];
    const float* att1= (const float*)d_in[14];
    const float* bo1 = (const float*)d_in[15];
    const float* g1  = (const float*)d_in[16];
    const float* be1 = (const float*)d_in[17];
    const float* Wl2 = (const float*)d_in[18];
    const float* bl2 = (const float*)d_in[19];
    const float* Wr2 = (const float*)d_in[20];
    const float* br2 = (const float*)d_in[21];
    const float* att2= (const float*)d_in[22];
    const float* bo2 = (const float*)d_in[23];
    const float* g2  = (const float*)d_in[24];
    const float* be2 = (const float*)d_in[25];
    const float* cW1 = (const float*)d_in[26];
    const float* cb1 = (const float*)d_in[27];
    const float* cW2 = (const float*)d_in[28];
    const float* cb2 = (const float*)d_in[29];

    char* ws = (char*)d_ws;
    float* xl = (float*)ws; ws += (size_t)N_NODES * 128 * 4;
    float* xr = (float*)ws; ws += (size_t)N_NODES * 128 * 4;
    float* h0 = (float*)ws; ws += (size_t)N_NODES * 128 * 4;
    float* h1 = (float*)ws; ws += (size_t)N_NODES * 128 * 4;
    float* h2 = (float*)ws; ws += (size_t)N_NODES * 32 * 4;
    int* rowptr  = (int*)ws; ws += (size_t)(N_NODES + 1) * 4;
    int* cursor  = (int*)ws; ws += (size_t)N_NODES * 4;
    int* deg     = (int*)ws; ws += (size_t)N_NODES * 4;
    int* csr_src = (int*)ws; ws += (size_t)ET * 4;

    // ---- CSR build (dst -> incoming src list) ----
    k_init_deg<<<(N_NODES + 255) / 256, 256, 0, stream>>>(deg, N_NODES);
    k_count<<<(N_EDGES + 255) / 256, 256, 0, stream>>>(dst, deg, N_EDGES);
    k_scan<<<1, 1024, 0, stream>>>(deg, rowptr, cursor, N_NODES);
    k_fill<<<(ET + 255) / 256, 256, 0, stream>>>(src, dst, cursor, csr_src);

    const int gx = (N_NODES + 63) / 64;          // 782 M-tiles
    const int grid64 = (N_NODES * 64 + 255) / 256;
    const int grid32 = (N_NODES * 32 + 255) / 256;

    // ---- layer 0: din=18 -> 4x32 concat=128 ----
    k_gemm_t<18, 128, 64><<<dim3(gx, 4), 256, 0, stream>>>(x, Wl0, bl0, Wr0, br0, xl, xr, N_NODES);
    k_gather_ln<128, 32, 2, false><<<grid64, 256, 0, stream>>>(
        xl, xr, att0, rowptr, csr_src, bo0, g0, be0, nullptr, h0, N_NODES);

    // ---- layer 1: din=128 -> 4x32 concat=128, residual ----
    k_gemm_t<128, 128, 64><<<dim3(gx, 4), 256, 0, stream>>>(h0, Wl1, bl1, Wr1, br1, xl, xr, N_NODES);
    k_gather_ln<128, 32, 2, true><<<grid64, 256, 0, stream>>>(
        xl, xr, att1, rowptr, csr_src, bo1, g1, be1, h0, h1, N_NODES);

    // ---- layer 2: din=128 -> 1x32 ----
    k_gemm_t<128, 32, 32><<<dim3(gx, 2), 256, 0, stream>>>(h1, Wl2, bl2, Wr2, br2, xl, xr, N_NODES);
    k_gather_ln<32, 32, 1, false><<<grid32, 256, 0, stream>>>(
        xl, xr, att2, rowptr, csr_src, bo2, g2, be2, nullptr, h2, N_NODES);

    // ---- classifier ----
    k_cls<<<(N_NODES + 255) / 256, 256, 0, stream>>>(h2, cW1, cb1, cW2, cb2, (float*)d_out, N_NODES);
}

// Round 4
// 775.624 us; speedup vs baseline: 1.1846x; 1.0118x over previous
//
#include <hip/hip_runtime.h>
#include <math.h>

#define N_NODES 50000
#define N_EDGES 800000
#define ET (N_EDGES + N_NODES)

// ---------------- CSR build ----------------

__global__ void k_init_deg(int* deg, int n) {
    int i = blockIdx.x * blockDim.x + threadIdx.x;
    if (i < n) deg[i] = 1;  // self-loop pre-counted
}

__global__ void k_count(const int* __restrict__ dst, int* __restrict__ deg, int e) {
    int i = blockIdx.x * blockDim.x + threadIdx.x;
    if (i < e) atomicAdd(&deg[dst[i]], 1);
}

// single-block scan via wave shuffles (3 barriers/chunk instead of 20)
__global__ void k_scan(const int* __restrict__ deg, int* __restrict__ rowptr,
                       int* __restrict__ cursor, int n) {
    __shared__ int wsum[16];
    __shared__ int carry_sh;
    int t = threadIdx.x;
    int wid = t >> 6, lane = t & 63;
    if (t == 0) carry_sh = 0;
    __syncthreads();
    for (int base = 0; base < n; base += 1024) {
        int i = base + t;
        int v = (i < n) ? deg[i] : 0;
        int x = v;
#pragma unroll
        for (int off = 1; off < 64; off <<= 1) {
            int u = __shfl_up(x, off, 64);
            if (lane >= off) x += u;
        }
        if (lane == 63) wsum[wid] = x;
        __syncthreads();
        if (wid == 0) {
            int wv = (lane < 16) ? wsum[lane] : 0;
            int y = wv;
#pragma unroll
            for (int off = 1; off < 16; off <<= 1) {
                int u = __shfl_up(y, off, 64);
                if (lane >= off) y += u;
            }
            if (lane < 16) wsum[lane] = y - wv;  // exclusive wave offsets
        }
        __syncthreads();
        int carry = carry_sh;
        int excl = carry + wsum[wid] + x - v;
        if (i < n) { rowptr[i] = excl; cursor[i] = excl; }
        __syncthreads();
        if (t == 1023) carry_sh = excl + v;
        __syncthreads();
    }
    if (t == 0) rowptr[n] = carry_sh;
}

__global__ void k_fill(const int* __restrict__ src, const int* __restrict__ dst,
                       int* __restrict__ cursor, int* __restrict__ csr_src) {
    int i = blockIdx.x * blockDim.x + threadIdx.x;
    if (i < N_EDGES) {
        int d = dst[i];
        int pos = atomicAdd(&cursor[d], 1);
        csr_src[pos] = src[i];
    } else if (i < ET) {
        int node = i - N_EDGES;
        int pos = atomicAdd(&cursor[node], 1);
        csr_src[pos] = node;
    }
}

// ---------------- degree sort (counting sort, 256 bins) ----------------

__global__ void k_zero256(int* hist) { hist[threadIdx.x] = 0; }

__global__ void k_hist(const int* __restrict__ deg, int* __restrict__ hist, int n) {
    __shared__ int lh[256];
    lh[threadIdx.x] = 0;
    __syncthreads();
    for (int i = blockIdx.x * 256 + threadIdx.x; i < n; i += gridDim.x * 256) {
        int b = deg[i]; b = (b > 255) ? 255 : b;
        atomicAdd(&lh[b], 1);
    }
    __syncthreads();
    if (lh[threadIdx.x]) atomicAdd(&hist[threadIdx.x], lh[threadIdx.x]);
}

__global__ void k_binstart(const int* __restrict__ hist, int* __restrict__ bincur) {
    __shared__ int sh[256];
    int t = threadIdx.x;
    int v = hist[t];
    sh[t] = v;
    __syncthreads();
    for (int off = 1; off < 256; off <<= 1) {
        int u = (t >= off) ? sh[t - off] : 0;
        __syncthreads();
        sh[t] += u;
        __syncthreads();
    }
    bincur[t] = sh[t] - v;  // exclusive
}

__global__ void k_scatter(const int* __restrict__ deg, int* __restrict__ bincur,
                          int* __restrict__ order, int n) {
    int i = blockIdx.x * blockDim.x + threadIdx.x;
    if (i < n) {
        int b = deg[i]; b = (b > 255) ? 255 : b;
        int pos = atomicAdd(&bincur[b], 1);
        order[pos] = i;
    }
}

// ---------------- tiled node GEMM (x-tile stored transposed: b128 both operands) ---

template<int K, int HD, int BN>
__global__ void k_gemm_t(const float* __restrict__ x,
                         const float* __restrict__ Wl, const float* __restrict__ bl,
                         const float* __restrict__ Wr, const float* __restrict__ br,
                         float* __restrict__ xl, float* __restrict__ xr, int n) {
    constexpr int BM = 64;
    constexpr int TM = 4;
    constexpr int TN = BN / 16;
    constexpr int CT_PER = HD / BN;
    __shared__ float xs[K][BM + 4];   // transposed: xs[k][node]
    __shared__ float ws[K][BN];
    int m0 = blockIdx.x * BM;
    int ct = blockIdx.y;
    const float* W = (ct < CT_PER) ? Wl : Wr;
    const float* bias = (ct < CT_PER) ? bl : br;
    float* o = (ct < CT_PER) ? xl : xr;
    int colBase = (ct % CT_PER) * BN;
    int t = threadIdx.x;
    for (int i = t; i < BM * K; i += 256) {
        int r = i / K, c = i % K;
        xs[c][r] = (m0 + r < n) ? x[(size_t)(m0 + r) * K + c] : 0.f;
    }
    for (int i = t; i < K * BN; i += 256) {
        int r = i / BN, c = i % BN;
        ws[r][c] = W[r * HD + colBase + c];
    }
    __syncthreads();
    int tr = t / 16, tc = t % 16;
    float acc[TM][TN];
#pragma unroll
    for (int j = 0; j < TN; j++) {
        float bv = bias[colBase + tc * TN + j];
#pragma unroll
        for (int i = 0; i < TM; i++) acc[i][j] = bv;
    }
#pragma unroll 2
    for (int k = 0; k < K; k++) {
        float4 av = *(const float4*)&xs[k][tr * TM];
        float a[TM] = {av.x, av.y, av.z, av.w};
#pragma unroll
        for (int j = 0; j < TN; j++) {
            float bb = ws[k][tc * TN + j];
#pragma unroll
            for (int i = 0; i < TM; i++) acc[i][j] = fmaf(a[i], bb, acc[i][j]);
        }
    }
#pragma unroll
    for (int i = 0; i < TM; i++) {
        int r = m0 + tr * TM + i;
        if (r < n) {
#pragma unroll
            for (int j = 0; j < TN; j++)
                o[(size_t)r * HD + colBase + tc * TN + j] = acc[i][j];
        }
    }
}

// ---------------- fused GATv2 gather + online softmax + LN + ELU (+res/+cls) ------
// VEC=8 dims/lane, L=HD/8 lanes/node, 64/L nodes/wave, degree-sorted node order.

template<int HD, int D, bool RES, bool CLS>
__global__ void k_gather_ln(const float* __restrict__ xl, const float* __restrict__ xr,
                            const float* __restrict__ att,
                            const int* __restrict__ rowptr, const int* __restrict__ csr_src,
                            const int* __restrict__ order,
                            const float* __restrict__ bo, const float* __restrict__ g,
                            const float* __restrict__ be, const float* res,
                            float* outh,
                            const float* cW1, const float* cb1,
                            const float* cW2, const float* cb2,
                            float* out, int n) {
    constexpr int VEC = 8;
    constexpr int L = HD / VEC;   // lanes per node
    constexpr int NPW = 64 / L;   // nodes per wave
    constexpr int G = D / VEC;    // lanes per head
    __shared__ float w1s[CLS ? 512 : 1];
    __shared__ float b1s[CLS ? 16 : 1];
    __shared__ float w2s[CLS ? 16 : 1];
    __shared__ float b2s[1];
    if (CLS) {
        int t = threadIdx.x;
        for (int i = t; i < 512; i += blockDim.x) w1s[i] = cW1[i];
        if (t < 16) { b1s[t] = cb1[t]; w2s[t] = cW2[t]; }
        if (t == 0) b2s[0] = cb2[0];
        __syncthreads();
    }
    int tid = blockIdx.x * blockDim.x + threadIdx.x;
    int wave = tid >> 6;
    int lane = tid & 63;
    int slot = wave * NPW + lane / L;
    if (slot >= n) return;
    int node = order[slot];
    int sub = lane % L;
    int f = sub * VEC;

    float xrv[8], attv[8], acc[8];
    {
        const float4* xrp = (const float4*)(xr + (size_t)node * HD + f);
        float4 a0 = xrp[0], a1 = xrp[1];
        xrv[0]=a0.x; xrv[1]=a0.y; xrv[2]=a0.z; xrv[3]=a0.w;
        xrv[4]=a1.x; xrv[5]=a1.y; xrv[6]=a1.z; xrv[7]=a1.w;
        const float4* ap = (const float4*)(att + f);
        float4 t0 = ap[0], t1 = ap[1];
        attv[0]=t0.x; attv[1]=t0.y; attv[2]=t0.z; attv[3]=t0.w;
        attv[4]=t1.x; attv[5]=t1.y; attv[6]=t1.z; attv[7]=t1.w;
#pragma unroll
        for (int i = 0; i < 8; i++) acc[i] = 0.f;
    }
    int e0 = rowptr[node];
    int deg = rowptr[node + 1] - e0;
    float m = -INFINITY, denom = 0.f;
    // 1-deep software pipeline on the gather
    int s = csr_src[e0];
    const float4* xp = (const float4*)(xl + (size_t)s * HD + f);
    float4 u0 = xp[0], u1 = xp[1];
    for (int j = 0; j < deg; j++) {
        float4 c0 = u0, c1 = u1;
        if (j + 1 < deg) {
            int s2 = csr_src[e0 + j + 1];
            const float4* xp2 = (const float4*)(xl + (size_t)s2 * HD + f);
            u0 = xp2[0]; u1 = xp2[1];
        }
        float xlv[8] = {c0.x, c0.y, c0.z, c0.w, c1.x, c1.y, c1.z, c1.w};
        float part = 0.f;
#pragma unroll
        for (int i = 0; i < 8; i++) {
            float e = xlv[i] + xrv[i];
            e = (e > 0.f) ? e : 0.2f * e;
            part = fmaf(e, attv[i], part);
        }
#pragma unroll
        for (int msk = G / 2; msk >= 1; msk >>= 1) part += __shfl_xor(part, msk, 64);
        float nm = fmaxf(m, part);
        float sc = __expf(m - nm);
        float w  = __expf(part - nm);
        denom = fmaf(denom, sc, w);
#pragma unroll
        for (int i = 0; i < 8; i++) acc[i] = fmaf(acc[i], sc, w * xlv[i]);
        m = nm;
    }
    float inv = 1.f / denom;
    // ---- +bo, LayerNorm over HD dims (L lanes), ELU ----
    float v[8];
    float s1 = 0.f;
#pragma unroll
    for (int i = 0; i < 8; i++) {
        v[i] = acc[i] * inv + bo[f + i];
        s1 += v[i];
    }
#pragma unroll
    for (int msk = L / 2; msk >= 1; msk >>= 1) s1 += __shfl_xor(s1, msk, 64);
    float mu = s1 * (1.f / HD);
    float q = 0.f;
#pragma unroll
    for (int i = 0; i < 8; i++) { float d = v[i] - mu; q += d * d; }
#pragma unroll
    for (int msk = L / 2; msk >= 1; msk >>= 1) q += __shfl_xor(q, msk, 64);
    float rstd = rsqrtf(q * (1.f / HD) + 1e-5f);
    float y[8];
#pragma unroll
    for (int i = 0; i < 8; i++) {
        float t = (v[i] - mu) * rstd * g[f + i] + be[f + i];
        t = (t > 0.f) ? t : expm1f(t);
        if (RES) t += res[(size_t)node * HD + f + i];
        y[i] = t;
    }
    if constexpr (!CLS) {
        float4 o0 = {y[0], y[1], y[2], y[3]};
        float4 o1 = {y[4], y[5], y[6], y[7]};
        float4* op = (float4*)(outh + (size_t)node * HD + f);
        op[0] = o0; op[1] = o1;
    } else {
        // fused classifier: out[node] = w2 . ELU(y@W1 + b1) + b2  (HD==32, L==4)
        float pj[16];
#pragma unroll
        for (int j = 0; j < 16; j++) pj[j] = 0.f;
#pragma unroll
        for (int k = 0; k < 8; k++) {
#pragma unroll
            for (int j = 0; j < 16; j++)
                pj[j] = fmaf(y[k], w1s[(f + k) * 16 + j], pj[j]);
        }
#pragma unroll
        for (int j = 0; j < 16; j++) {
            pj[j] += __shfl_xor(pj[j], 1, 64);
            pj[j] += __shfl_xor(pj[j], 2, 64);
        }
        float o = b2s[0];
#pragma unroll
        for (int j = 0; j < 16; j++) {
            float a2 = pj[j] + b1s[j];
            a2 = (a2 > 0.f) ? a2 : expm1f(a2);
            o = fmaf(a2, w2s[j], o);
        }
        if (sub == 0) out[node] = o;
    }
}

// ---------------- launch ----------------

extern "C" void kernel_launch(void* const* d_in, const int* in_sizes, int n_in,
                              void* d_out, int out_size, void* d_ws, size_t ws_size,
                              hipStream_t stream) {
    (void)in_sizes; (void)n_in; (void)out_size; (void)ws_size;
    const float* x  = (const float*)d_in[0];
    const int*   ei = (const int*)d_in[1];
    const int* src = ei;
    const int* dst = ei + N_EDGES;

    const float* Wl0 = (const float*)d_in[2];
    const float* bl0 = (const float*)d_in[3];
    const float* Wr0 = (const float*)d_in[4];
    const float* br0 = (const float*)d_in[5];
    const float* att0= (const float*)d_in[6];
    const float* bo0 = (const float*)d_in[7];
    const float* g0  = (const float*)d_in[8];
    const float* be0 = (const float*)d_in[9];
    const float* Wl1 = (const float*)d_in[10];
    const float* bl1 = (const float*)d_in[11];
    const float* Wr1 = (const float*)d_in[12];
    const float* br1 = (const float*)d_in[13];
    const float* att1= (const float*)d_in[14];
    const float* bo1 = (const float*)d_in[15];
    const float* g1  = (const float*)d_in[16];
    const float* be1 = (const float*)d_in[17];
    const float* Wl2 = (const float*)d_in[18];
    const float* bl2 = (const float*)d_in[19];
    const float* Wr2 = (const float*)d_in[20];
    const float* br2 = (const float*)d_in[21];
    const float* att2= (const float*)d_in[22];
    const float* bo2 = (const float*)d_in[23];
    const float* g2  = (const float*)d_in[24];
    const float* be2 = (const float*)d_in[25];
    const float* cW1 = (const float*)d_in[26];
    const float* cb1 = (const float*)d_in[27];
    const float* cW2 = (const float*)d_in[28];
    const float* cb2 = (const float*)d_in[29];

    char* ws = (char*)d_ws;
    float* xl = (float*)ws; ws += (size_t)N_NODES * 128 * 4;
    float* xr = (float*)ws; ws += (size_t)N_NODES * 128 * 4;
    float* h0 = (float*)ws; ws += (size_t)N_NODES * 128 * 4;
    float* h1 = (float*)ws; ws += (size_t)N_NODES * 128 * 4;
    int* rowptr  = (int*)ws; ws += (size_t)(N_NODES + 1) * 4;
    int* cursor  = (int*)ws; ws += (size_t)N_NODES * 4;
    int* deg     = (int*)ws; ws += (size_t)N_NODES * 4;
    int* csr_src = (int*)ws; ws += (size_t)ET * 4;
    int* hist    = (int*)ws; ws += 256 * 4;
    int* bincur  = (int*)ws; ws += 256 * 4;
    int* order   = (int*)ws; ws += (size_t)N_NODES * 4;

    // ---- CSR build ----
    k_init_deg<<<(N_NODES + 255) / 256, 256, 0, stream>>>(deg, N_NODES);
    k_count<<<(N_EDGES + 255) / 256, 256, 0, stream>>>(dst, deg, N_EDGES);
    k_scan<<<1, 1024, 0, stream>>>(deg, rowptr, cursor, N_NODES);
    k_fill<<<(ET + 255) / 256, 256, 0, stream>>>(src, dst, cursor, csr_src);
    // ---- degree sort ----
    k_zero256<<<1, 256, 0, stream>>>(hist);
    k_hist<<<64, 256, 0, stream>>>(deg, hist, N_NODES);
    k_binstart<<<1, 256, 0, stream>>>(hist, bincur);
    k_scatter<<<(N_NODES + 255) / 256, 256, 0, stream>>>(deg, bincur, order, N_NODES);

    const int gx = (N_NODES + 63) / 64;
    const int gridG128 = (N_NODES + 15) / 16;   // 16 nodes/block (VEC=8, HD=128)
    const int gridG32  = (N_NODES + 63) / 64;   // 64 nodes/block (VEC=8, HD=32)

    // ---- layer 0 ----
    k_gemm_t<18, 128, 64><<<dim3(gx, 4), 256, 0, stream>>>(x, Wl0, bl0, Wr0, br0, xl, xr, N_NODES);
    k_gather_ln<128, 32, false, false><<<gridG128, 256, 0, stream>>>(
        xl, xr, att0, rowptr, csr_src, order, bo0, g0, be0, nullptr, h0,
        nullptr, nullptr, nullptr, nullptr, nullptr, N_NODES);

    // ---- layer 1 (residual) ----
    k_gemm_t<128, 128, 64><<<dim3(gx, 4), 256, 0, stream>>>(h0, Wl1, bl1, Wr1, br1, xl, xr, N_NODES);
    k_gather_ln<128, 32, true, false><<<gridG128, 256, 0, stream>>>(
        xl, xr, att1, rowptr, csr_src, order, bo1, g1, be1, h0, h1,
        nullptr, nullptr, nullptr, nullptr, nullptr, N_NODES);

    // ---- layer 2 + fused classifier ----
    k_gemm_t<128, 32, 32><<<dim3(gx, 2), 256, 0, stream>>>(h1, Wl2, bl2, Wr2, br2, xl, xr, N_NODES);
    k_gather_ln<32, 32, false, true><<<gridG32, 256, 0, stream>>>(
        xl, xr, att2, rowptr, csr_src, order, bo2, g2, be2, nullptr, nullptr,
        cW1, cb1, cW2, cb2, (float*)d_out, N_NODES);
}

// Round 6
// 631.842 us; speedup vs baseline: 1.4542x; 1.2276x over previous
//
#include <hip/hip_runtime.h>
#include <math.h>

#define N_NODES 50000
#define N_EDGES 800000
#define ET (N_EDGES + N_NODES)

// ---------------- CSR build ----------------

__global__ void k_init_deg(int* deg, int n) {
    int i = blockIdx.x * blockDim.x + threadIdx.x;
    if (i < n) deg[i] = 1;  // self-loop pre-counted
}

__global__ void k_count(const int* __restrict__ dst, int* __restrict__ deg, int e) {
    int i = blockIdx.x * blockDim.x + threadIdx.x;
    if (i < e) atomicAdd(&deg[dst[i]], 1);
}

// single-block scan via wave shuffles
__global__ void k_scan(const int* __restrict__ deg, int* __restrict__ rowptr,
                       int* __restrict__ cursor, int n) {
    __shared__ int wsum[16];
    __shared__ int carry_sh;
    int t = threadIdx.x;
    int wid = t >> 6, lane = t & 63;
    if (t == 0) carry_sh = 0;
    __syncthreads();
    for (int base = 0; base < n; base += 1024) {
        int i = base + t;
        int v = (i < n) ? deg[i] : 0;
        int x = v;
#pragma unroll
        for (int off = 1; off < 64; off <<= 1) {
            int u = __shfl_up(x, off, 64);
            if (lane >= off) x += u;
        }
        if (lane == 63) wsum[wid] = x;
        __syncthreads();
        if (wid == 0) {
            int wv = (lane < 16) ? wsum[lane] : 0;
            int y = wv;
#pragma unroll
            for (int off = 1; off < 16; off <<= 1) {
                int u = __shfl_up(y, off, 64);
                if (lane >= off) y += u;
            }
            if (lane < 16) wsum[lane] = y - wv;  // exclusive wave offsets
        }
        __syncthreads();
        int carry = carry_sh;
        int excl = carry + wsum[wid] + x - v;
        if (i < n) { rowptr[i] = excl; cursor[i] = excl; }
        __syncthreads();
        if (t == 1023) carry_sh = excl + v;
        __syncthreads();
    }
    if (t == 0) rowptr[n] = carry_sh;
}

__global__ void k_fill(const int* __restrict__ src, const int* __restrict__ dst,
                       int* __restrict__ cursor, int* __restrict__ csr_src) {
    int i = blockIdx.x * blockDim.x + threadIdx.x;
    if (i < N_EDGES) {
        int d = dst[i];
        int pos = atomicAdd(&cursor[d], 1);
        csr_src[pos] = src[i];
    } else if (i < ET) {
        int node = i - N_EDGES;
        int pos = atomicAdd(&cursor[node], 1);
        csr_src[pos] = node;
    }
}

// ---------------- degree sort (counting sort, 256 bins) ----------------

__global__ void k_zero256(int* hist) { hist[threadIdx.x] = 0; }

__global__ void k_hist(const int* __restrict__ deg, int* __restrict__ hist, int n) {
    __shared__ int lh[256];
    lh[threadIdx.x] = 0;
    __syncthreads();
    for (int i = blockIdx.x * 256 + threadIdx.x; i < n; i += gridDim.x * 256) {
        int b = deg[i]; b = (b > 255) ? 255 : b;
        atomicAdd(&lh[b], 1);
    }
    __syncthreads();
    if (lh[threadIdx.x]) atomicAdd(&hist[threadIdx.x], lh[threadIdx.x]);
}

__global__ void k_binstart(const int* __restrict__ hist, int* __restrict__ bincur) {
    __shared__ int sh[256];
    int t = threadIdx.x;
    int v = hist[t];
    sh[t] = v;
    __syncthreads();
    for (int off = 1; off < 256; off <<= 1) {
        int u = (t >= off) ? sh[t - off] : 0;
        __syncthreads();
        sh[t] += u;
        __syncthreads();
    }
    bincur[t] = sh[t] - v;  // exclusive
}

// two-level scatter: LDS-atomic local rank + one global atomicAdd per
// non-empty bin per block (Guideline 12 — kills the hot-bin serialization)
__global__ void k_scatter(const int* __restrict__ deg, int* __restrict__ bincur,
                          int* __restrict__ order, int n) {
    __shared__ int lcount[256];
    __shared__ int lbase[256];
    int t = threadIdx.x;
    lcount[t] = 0;
    __syncthreads();
    int i = blockIdx.x * 256 + t;
    int b = 0, rank = 0;
    bool valid = (i < n);
    if (valid) {
        b = deg[i]; b = (b > 255) ? 255 : b;
        rank = atomicAdd(&lcount[b], 1);   // LDS atomic
    }
    __syncthreads();
    if (lcount[t] > 0) lbase[t] = atomicAdd(&bincur[t], lcount[t]);
    __syncthreads();
    if (valid) order[lbase[b] + rank] = i;
}

// ---------------- tiled node GEMM (x-tile stored transposed: b128 both operands) ---

template<int K, int HD, int BN>
__global__ void k_gemm_t(const float* __restrict__ x,
                         const float* __restrict__ Wl, const float* __restrict__ bl,
                         const float* __restrict__ Wr, const float* __restrict__ br,
                         float* __restrict__ xl, float* __restrict__ xr, int n) {
    constexpr int BM = 64;
    constexpr int TM = 4;
    constexpr int TN = BN / 16;
    constexpr int CT_PER = HD / BN;
    __shared__ float xs[K][BM + 4];   // transposed: xs[k][node]
    __shared__ float ws[K][BN];
    int m0 = blockIdx.x * BM;
    int ct = blockIdx.y;
    const float* W = (ct < CT_PER) ? Wl : Wr;
    const float* bias = (ct < CT_PER) ? bl : br;
    float* o = (ct < CT_PER) ? xl : xr;
    int colBase = (ct % CT_PER) * BN;
    int t = threadIdx.x;
    for (int i = t; i < BM * K; i += 256) {
        int r = i / K, c = i % K;
        xs[c][r] = (m0 + r < n) ? x[(size_t)(m0 + r) * K + c] : 0.f;
    }
    for (int i = t; i < K * BN; i += 256) {
        int r = i / BN, c = i % BN;
        ws[r][c] = W[r * HD + colBase + c];
    }
    __syncthreads();
    int tr = t / 16, tc = t % 16;
    float acc[TM][TN];
#pragma unroll
    for (int j = 0; j < TN; j++) {
        float bv = bias[colBase + tc * TN + j];
#pragma unroll
        for (int i = 0; i < TM; i++) acc[i][j] = bv;
    }
#pragma unroll 2
    for (int k = 0; k < K; k++) {
        float4 av = *(const float4*)&xs[k][tr * TM];
        float a[TM] = {av.x, av.y, av.z, av.w};
#pragma unroll
        for (int j = 0; j < TN; j++) {
            float bb = ws[k][tc * TN + j];
#pragma unroll
            for (int i = 0; i < TM; i++) acc[i][j] = fmaf(a[i], bb, acc[i][j]);
        }
    }
#pragma unroll
    for (int i = 0; i < TM; i++) {
        int r = m0 + tr * TM + i;
        if (r < n) {
#pragma unroll
            for (int j = 0; j < TN; j++)
                o[(size_t)r * HD + colBase + tc * TN + j] = acc[i][j];
        }
    }
}

// ---------------- fused GATv2 gather + online softmax + LN + ELU (+res/+cls) ------
// VEC=8 dims/lane, L=HD/8 lanes/node, 64/L nodes/wave, degree-sorted node order.

template<int HD, int D, bool RES, bool CLS>
__global__ void k_gather_ln(const float* __restrict__ xl, const float* __restrict__ xr,
                            const float* __restrict__ att,
                            const int* __restrict__ rowptr, const int* __restrict__ csr_src,
                            const int* __restrict__ order,
                            const float* __restrict__ bo, const float* __restrict__ g,
                            const float* __restrict__ be, const float* res,
                            float* outh,
                            const float* cW1, const float* cb1,
                            const float* cW2, const float* cb2,
                            float* out, int n) {
    constexpr int VEC = 8;
    constexpr int L = HD / VEC;   // lanes per node
    constexpr int NPW = 64 / L;   // nodes per wave
    constexpr int G = D / VEC;    // lanes per head
    __shared__ float w1s[CLS ? 512 : 1];
    __shared__ float b1s[CLS ? 16 : 1];
    __shared__ float w2s[CLS ? 16 : 1];
    __shared__ float b2s[1];
    if (CLS) {
        int t = threadIdx.x;
        for (int i = t; i < 512; i += blockDim.x) w1s[i] = cW1[i];
        if (t < 16) { b1s[t] = cb1[t]; w2s[t] = cW2[t]; }
        if (t == 0) b2s[0] = cb2[0];
        __syncthreads();
    }
    int tid = blockIdx.x * blockDim.x + threadIdx.x;
    int wave = tid >> 6;
    int lane = tid & 63;
    int slot = wave * NPW + lane / L;
    if (slot >= n) return;
    int node = order[slot];
    int sub = lane % L;
    int f = sub * VEC;

    float xrv[8], attv[8], acc[8];
    {
        const float4* xrp = (const float4*)(xr + (size_t)node * HD + f);
        float4 a0 = xrp[0], a1 = xrp[1];
        xrv[0]=a0.x; xrv[1]=a0.y; xrv[2]=a0.z; xrv[3]=a0.w;
        xrv[4]=a1.x; xrv[5]=a1.y; xrv[6]=a1.z; xrv[7]=a1.w;
        const float4* ap = (const float4*)(att + f);
        float4 t0 = ap[0], t1 = ap[1];
        attv[0]=t0.x; attv[1]=t0.y; attv[2]=t0.z; attv[3]=t0.w;
        attv[4]=t1.x; attv[5]=t1.y; attv[6]=t1.z; attv[7]=t1.w;
#pragma unroll
        for (int i = 0; i < 8; i++) acc[i] = 0.f;
    }
    int e0 = rowptr[node];
    int deg = rowptr[node + 1] - e0;
    float m = -INFINITY, denom = 0.f;
    // 1-deep software pipeline on the gather
    int s = csr_src[e0];
    const float4* xp = (const float4*)(xl + (size_t)s * HD + f);
    float4 u0 = xp[0], u1 = xp[1];
    for (int j = 0; j < deg; j++) {
        float4 c0 = u0, c1 = u1;
        if (j + 1 < deg) {
            int s2 = csr_src[e0 + j + 1];
            const float4* xp2 = (const float4*)(xl + (size_t)s2 * HD + f);
            u0 = xp2[0]; u1 = xp2[1];
        }
        float xlv[8] = {c0.x, c0.y, c0.z, c0.w, c1.x, c1.y, c1.z, c1.w};
        float part = 0.f;
#pragma unroll
        for (int i = 0; i < 8; i++) {
            float e = xlv[i] + xrv[i];
            e = (e > 0.f) ? e : 0.2f * e;
            part = fmaf(e, attv[i], part);
        }
#pragma unroll
        for (int msk = G / 2; msk >= 1; msk >>= 1) part += __shfl_xor(part, msk, 64);
        float nm = fmaxf(m, part);
        float sc = __expf(m - nm);
        float w  = __expf(part - nm);
        denom = fmaf(denom, sc, w);
#pragma unroll
        for (int i = 0; i < 8; i++) acc[i] = fmaf(acc[i], sc, w * xlv[i]);
        m = nm;
    }
    float inv = 1.f / denom;
    // ---- +bo, LayerNorm over HD dims (L lanes), ELU ----
    float v[8];
    float s1 = 0.f;
#pragma unroll
    for (int i = 0; i < 8; i++) {
        v[i] = acc[i] * inv + bo[f + i];
        s1 += v[i];
    }
#pragma unroll
    for (int msk = L / 2; msk >= 1; msk >>= 1) s1 += __shfl_xor(s1, msk, 64);
    float mu = s1 * (1.f / HD);
    float q = 0.f;
#pragma unroll
    for (int i = 0; i < 8; i++) { float d = v[i] - mu; q += d * d; }
#pragma unroll
    for (int msk = L / 2; msk >= 1; msk >>= 1) q += __shfl_xor(q, msk, 64);
    float rstd = rsqrtf(q * (1.f / HD) + 1e-5f);
    float y[8];
#pragma unroll
    for (int i = 0; i < 8; i++) {
        float t = (v[i] - mu) * rstd * g[f + i] + be[f + i];
        t = (t > 0.f) ? t : expm1f(t);
        if (RES) t += res[(size_t)node * HD + f + i];
        y[i] = t;
    }
    if constexpr (!CLS) {
        float4 o0 = {y[0], y[1], y[2], y[3]};
        float4 o1 = {y[4], y[5], y[6], y[7]};
        float4* op = (float4*)(outh + (size_t)node * HD + f);
        op[0] = o0; op[1] = o1;
    } else {
        // fused classifier: out[node] = w2 . ELU(y@W1 + b1) + b2  (HD==32, L==4)
        float pj[16];
#pragma unroll
        for (int j = 0; j < 16; j++) pj[j] = 0.f;
#pragma unroll
        for (int k = 0; k < 8; k++) {
#pragma unroll
            for (int j = 0; j < 16; j++)
                pj[j] = fmaf(y[k], w1s[(f + k) * 16 + j], pj[j]);
        }
#pragma unroll
        for (int j = 0; j < 16; j++) {
            pj[j] += __shfl_xor(pj[j], 1, 64);
            pj[j] += __shfl_xor(pj[j], 2, 64);
        }
        float o = b2s[0];
#pragma unroll
        for (int j = 0; j < 16; j++) {
            float a2 = pj[j] + b1s[j];
            a2 = (a2 > 0.f) ? a2 : expm1f(a2);
            o = fmaf(a2, w2s[j], o);
        }
        if (sub == 0) out[node] = o;
    }
}

// ---------------- launch ----------------

extern "C" void kernel_launch(void* const* d_in, const int* in_sizes, int n_in,
                              void* d_out, int out_size, void* d_ws, size_t ws_size,
                              hipStream_t stream) {
    (void)in_sizes; (void)n_in; (void)out_size; (void)ws_size;
    const float* x  = (const float*)d_in[0];
    const int*   ei = (const int*)d_in[1];
    const int* src = ei;
    const int* dst = ei + N_EDGES;

    const float* Wl0 = (const float*)d_in[2];
    const float* bl0 = (const float*)d_in[3];
    const float* Wr0 = (const float*)d_in[4];
    const float* br0 = (const float*)d_in[5];
    const float* att0= (const float*)d_in[6];
    const float* bo0 = (const float*)d_in[7];
    const float* g0  = (const float*)d_in[8];
    const float* be0 = (const float*)d_in[9];
    const float* Wl1 = (const float*)d_in[10];
    const float* bl1 = (const float*)d_in[11];
    const float* Wr1 = (const float*)d_in[12];
    const float* br1 = (const float*)d_in[13];
    const float* att1= (const float*)d_in[14];
    const float* bo1 = (const float*)d_in[15];
    const float* g1  = (const float*)d_in[16];
    const float* be1 = (const float*)d_in[17];
    const float* Wl2 = (const float*)d_in[18];
    const float* bl2 = (const float*)d_in[19];
    const float* Wr2 = (const float*)d_in[20];
    const float* br2 = (const float*)d_in[21];
    const float* att2= (const float*)d_in[22];
    const float* bo2 = (const float*)d_in[23];
    const float* g2  = (const float*)d_in[24];
    const float* be2 = (const float*)d_in[25];
    const float* cW1 = (const float*)d_in[26];
    const float* cb1 = (const float*)d_in[27];
    const float* cW2 = (const float*)d_in[28];
    const float* cb2 = (const float*)d_in[29];

    char* ws = (char*)d_ws;
    float* xl = (float*)ws; ws += (size_t)N_NODES * 128 * 4;
    float* xr = (float*)ws; ws += (size_t)N_NODES * 128 * 4;
    float* h0 = (float*)ws; ws += (size_t)N_NODES * 128 * 4;
    float* h1 = (float*)ws; ws += (size_t)N_NODES * 128 * 4;
    int* rowptr  = (int*)ws; ws += (size_t)(N_NODES + 1) * 4;
    int* cursor  = (int*)ws; ws += (size_t)N_NODES * 4;
    int* deg     = (int*)ws; ws += (size_t)N_NODES * 4;
    int* csr_src = (int*)ws; ws += (size_t)ET * 4;
    int* hist    = (int*)ws; ws += 256 * 4;
    int* bincur  = (int*)ws; ws += 256 * 4;
    int* order   = (int*)ws; ws += (size_t)N_NODES * 4;

    // ---- CSR build ----
    k_init_deg<<<(N_NODES + 255) / 256, 256, 0, stream>>>(deg, N_NODES);
    k_count<<<(N_EDGES + 255) / 256, 256, 0, stream>>>(dst, deg, N_EDGES);
    k_scan<<<1, 1024, 0, stream>>>(deg, rowptr, cursor, N_NODES);
    k_fill<<<(ET + 255) / 256, 256, 0, stream>>>(src, dst, cursor, csr_src);
    // ---- degree sort ----
    k_zero256<<<1, 256, 0, stream>>>(hist);
    k_hist<<<64, 256, 0, stream>>>(deg, hist, N_NODES);
    k_binstart<<<1, 256, 0, stream>>>(hist, bincur);
    k_scatter<<<(N_NODES + 255) / 256, 256, 0, stream>>>(deg, bincur, order, N_NODES);

    const int gx = (N_NODES + 63) / 64;
    const int gridG128 = (N_NODES + 15) / 16;   // 16 nodes/block (VEC=8, HD=128)
    const int gridG32  = (N_NODES + 63) / 64;   // 64 nodes/block (VEC=8, HD=32)

    // ---- layer 0 ----
    k_gemm_t<18, 128, 64><<<dim3(gx, 4), 256, 0, stream>>>(x, Wl0, bl0, Wr0, br0, xl, xr, N_NODES);
    k_gather_ln<128, 32, false, false><<<gridG128, 256, 0, stream>>>(
        xl, xr, att0, rowptr, csr_src, order, bo0, g0, be0, nullptr, h0,
        nullptr, nullptr, nullptr, nullptr, nullptr, N_NODES);

    // ---- layer 1 (residual) ----
    k_gemm_t<128, 128, 64><<<dim3(gx, 4), 256, 0, stream>>>(h0, Wl1, bl1, Wr1, br1, xl, xr, N_NODES);
    k_gather_ln<128, 32, true, false><<<gridG128, 256, 0, stream>>>(
        xl, xr, att1, rowptr, csr_src, order, bo1, g1, be1, h0, h1,
        nullptr, nullptr, nullptr, nullptr, nullptr, N_NODES);

    // ---- layer 2 + fused classifier ----
    k_gemm_t<128, 32, 32><<<dim3(gx, 2), 256, 0, stream>>>(h1, Wl2, bl2, Wr2, br2, xl, xr, N_NODES);
    k_gather_ln<32, 32, false, true><<<gridG32, 256, 0, stream>>>(
        xl, xr, att2, rowptr, csr_src, order, bo2, g2, be2, nullptr, nullptr,
        cW1, cb1, cW2, cb2, (float*)d_out, N_NODES);
}

// Round 7
// 556.328 us; speedup vs baseline: 1.6516x; 1.1357x over previous
//
#include <hip/hip_runtime.h>
#include <math.h>

#define N_NODES 50000
#define N_EDGES 800000
#define ET (N_EDGES + N_NODES)

// ---------------- CSR build ----------------

__global__ void k_init_deg(int* deg, int n) {
    int i = blockIdx.x * blockDim.x + threadIdx.x;
    if (i < n) deg[i] = 1;  // self-loop pre-counted
}

__global__ void k_count(const int* __restrict__ dst, int* __restrict__ deg, int e) {
    int i = blockIdx.x * blockDim.x + threadIdx.x;
    if (i < e) atomicAdd(&deg[dst[i]], 1);
}

// single-block scan via wave shuffles
__global__ void k_scan(const int* __restrict__ deg, int* __restrict__ rowptr,
                       int* __restrict__ cursor, int n) {
    __shared__ int wsum[16];
    __shared__ int carry_sh;
    int t = threadIdx.x;
    int wid = t >> 6, lane = t & 63;
    if (t == 0) carry_sh = 0;
    __syncthreads();
    for (int base = 0; base < n; base += 1024) {
        int i = base + t;
        int v = (i < n) ? deg[i] : 0;
        int x = v;
#pragma unroll
        for (int off = 1; off < 64; off <<= 1) {
            int u = __shfl_up(x, off, 64);
            if (lane >= off) x += u;
        }
        if (lane == 63) wsum[wid] = x;
        __syncthreads();
        if (wid == 0) {
            int wv = (lane < 16) ? wsum[lane] : 0;
            int y = wv;
#pragma unroll
            for (int off = 1; off < 16; off <<= 1) {
                int u = __shfl_up(y, off, 64);
                if (lane >= off) y += u;
            }
            if (lane < 16) wsum[lane] = y - wv;  // exclusive wave offsets
        }
        __syncthreads();
        int carry = carry_sh;
        int excl = carry + wsum[wid] + x - v;
        if (i < n) { rowptr[i] = excl; cursor[i] = excl; }
        __syncthreads();
        if (t == 1023) carry_sh = excl + v;
        __syncthreads();
    }
    if (t == 0) rowptr[n] = carry_sh;
}

__global__ void k_fill(const int* __restrict__ src, const int* __restrict__ dst,
                       int* __restrict__ cursor, int* __restrict__ csr_src) {
    int i = blockIdx.x * blockDim.x + threadIdx.x;
    if (i < N_EDGES) {
        int d = dst[i];
        int pos = atomicAdd(&cursor[d], 1);
        csr_src[pos] = src[i];
    } else if (i < ET) {
        int node = i - N_EDGES;
        int pos = atomicAdd(&cursor[node], 1);
        csr_src[pos] = node;
    }
}

// ---------------- degree sort (counting sort, 256 bins) ----------------

__global__ void k_zero256(int* hist) { hist[threadIdx.x] = 0; }

__global__ void k_hist(const int* __restrict__ deg, int* __restrict__ hist, int n) {
    __shared__ int lh[256];
    lh[threadIdx.x] = 0;
    __syncthreads();
    for (int i = blockIdx.x * 256 + threadIdx.x; i < n; i += gridDim.x * 256) {
        int b = deg[i]; b = (b > 255) ? 255 : b;
        atomicAdd(&lh[b], 1);
    }
    __syncthreads();
    if (lh[threadIdx.x]) atomicAdd(&hist[threadIdx.x], lh[threadIdx.x]);
}

__global__ void k_binstart(const int* __restrict__ hist, int* __restrict__ bincur) {
    __shared__ int sh[256];
    int t = threadIdx.x;
    int v = hist[t];
    sh[t] = v;
    __syncthreads();
    for (int off = 1; off < 256; off <<= 1) {
        int u = (t >= off) ? sh[t - off] : 0;
        __syncthreads();
        sh[t] += u;
        __syncthreads();
    }
    bincur[t] = sh[t] - v;  // exclusive
}

// two-level scatter: LDS-atomic local rank + one global atomicAdd per
// non-empty bin per block
__global__ void k_scatter(const int* __restrict__ deg, int* __restrict__ bincur,
                          int* __restrict__ order, int n) {
    __shared__ int lcount[256];
    __shared__ int lbase[256];
    int t = threadIdx.x;
    lcount[t] = 0;
    __syncthreads();
    int i = blockIdx.x * 256 + t;
    int b = 0, rank = 0;
    bool valid = (i < n);
    if (valid) {
        b = deg[i]; b = (b > 255) ? 255 : b;
        rank = atomicAdd(&lcount[b], 1);   // LDS atomic
    }
    __syncthreads();
    if (lcount[t] > 0) lbase[t] = atomicAdd(&bincur[t], lcount[t]);
    __syncthreads();
    if (valid) order[lbase[b] + rank] = i;
}

// ---------------- tiled node GEMM, K-chunked, 8x8 microtile ----------------
// BM=128 nodes, BN output cols, BK K-chunk. 256 threads as 16x16 grid.
// x-tile staged TRANSPOSED (xs[k][node]) with stride-1 conflict-free LDS
// writes (lanes map to consecutive rows; stride-K global reads are
// L1-absorbed: 128 rows x 2 lines = 16 KB < 32 KB L1).
// LDS ~33 KB -> 4 blocks/CU (vs 67.5 KB -> 2 before).

template<int K, int BK, int HD, int BN, int TM, int TN>
__launch_bounds__(256, 4)
__global__ void k_gemm_t(const float* __restrict__ x,
                         const float* __restrict__ Wl, const float* __restrict__ bl,
                         const float* __restrict__ Wr, const float* __restrict__ br,
                         float* __restrict__ xl, float* __restrict__ xr, int n) {
    constexpr int BM = 128;
    constexpr int CT_PER = HD / BN;
    __shared__ float xs[BK][BM + 4];
    __shared__ float ws[BK][BN];
    int m0 = blockIdx.x * BM;
    int ct = blockIdx.y;
    const float* W  = (ct < CT_PER) ? Wl : Wr;
    const float* bv = (ct < CT_PER) ? bl : br;
    float* o        = (ct < CT_PER) ? xl : xr;
    int colBase = (ct % CT_PER) * BN;
    int t = threadIdx.x;
    int tr = t >> 4, tc = t & 15;   // 16x16 thread grid
    float acc[TM][TN];
#pragma unroll
    for (int j = 0; j < TN; j++) {
        float b0 = bv[colBase + tc * TN + j];
#pragma unroll
        for (int i = 0; i < TM; i++) acc[i][j] = b0;
    }
    for (int k0 = 0; k0 < K; k0 += BK) {
        // ---- stage x-tile transposed ----
        if constexpr ((BK % 4) == 0) {
            constexpr int NFL4 = BM * BK / 4;
            for (int idx = t; idx < NFL4; idx += 256) {
                int r  = idx % BM;   // consecutive lanes -> consecutive r
                int c0 = idx / BM;
                float4 v = {0.f, 0.f, 0.f, 0.f};
                int row = m0 + r;
                if (row < n) v = *(const float4*)&x[(size_t)row * K + k0 + c0 * 4];
                xs[c0 * 4 + 0][r] = v.x;
                xs[c0 * 4 + 1][r] = v.y;
                xs[c0 * 4 + 2][r] = v.z;
                xs[c0 * 4 + 3][r] = v.w;
            }
        } else {
            for (int idx = t; idx < BM * BK; idx += 256) {
                int r = idx % BM;
                int c = idx / BM;
                float v = 0.f;
                int row = m0 + r;
                if (row < n) v = x[(size_t)row * K + k0 + c];
                xs[c][r] = v;
            }
        }
        // ---- stage W-tile (coalesced, stride-1 writes) ----
        for (int idx = t; idx < BK * BN; idx += 256) {
            int r = idx / BN, c = idx % BN;
            ws[r][c] = W[(size_t)(k0 + r) * HD + colBase + c];
        }
        __syncthreads();
#pragma unroll 2
        for (int k = 0; k < BK; k++) {
            float a[TM], b[TN];
#pragma unroll
            for (int q = 0; q < TM; q += 4)
                *(float4*)&a[q] = *(const float4*)&xs[k][tr * TM + q];
            if constexpr (TN == 8) {
                *(float4*)&b[0] = *(const float4*)&ws[k][tc * TN];
                *(float4*)&b[4] = *(const float4*)&ws[k][tc * TN + 4];
            } else if constexpr (TN == 4) {
                *(float4*)&b[0] = *(const float4*)&ws[k][tc * TN];
            } else {
                *(float2*)&b[0] = *(const float2*)&ws[k][tc * TN];
            }
#pragma unroll
            for (int i = 0; i < TM; i++)
#pragma unroll
                for (int j = 0; j < TN; j++)
                    acc[i][j] = fmaf(a[i], b[j], acc[i][j]);
        }
        __syncthreads();
    }
#pragma unroll
    for (int i = 0; i < TM; i++) {
        int r = m0 + tr * TM + i;
        if (r < n) {
            if constexpr ((TN % 4) == 0) {
#pragma unroll
                for (int j = 0; j < TN; j += 4)
                    *(float4*)&o[(size_t)r * HD + colBase + tc * TN + j] = *(float4*)&acc[i][j];
            } else {
                *(float2*)&o[(size_t)r * HD + colBase + tc * TN] = *(float2*)&acc[i][0];
            }
        }
    }
}

// ---------------- fused GATv2 gather + online softmax + LN + ELU (+res/+cls) ------
// VEC=8 dims/lane, L=HD/8 lanes/node, 64/L nodes/wave, degree-sorted node order.

template<int HD, int D, bool RES, bool CLS>
__global__ void k_gather_ln(const float* __restrict__ xl, const float* __restrict__ xr,
                            const float* __restrict__ att,
                            const int* __restrict__ rowptr, const int* __restrict__ csr_src,
                            const int* __restrict__ order,
                            const float* __restrict__ bo, const float* __restrict__ g,
                            const float* __restrict__ be, const float* res,
                            float* outh,
                            const float* cW1, const float* cb1,
                            const float* cW2, const float* cb2,
                            float* out, int n) {
    constexpr int VEC = 8;
    constexpr int L = HD / VEC;   // lanes per node
    constexpr int NPW = 64 / L;   // nodes per wave
    constexpr int G = D / VEC;    // lanes per head
    __shared__ float w1s[CLS ? 512 : 1];
    __shared__ float b1s[CLS ? 16 : 1];
    __shared__ float w2s[CLS ? 16 : 1];
    __shared__ float b2s[1];
    if (CLS) {
        int t = threadIdx.x;
        for (int i = t; i < 512; i += blockDim.x) w1s[i] = cW1[i];
        if (t < 16) { b1s[t] = cb1[t]; w2s[t] = cW2[t]; }
        if (t == 0) b2s[0] = cb2[0];
        __syncthreads();
    }
    int tid = blockIdx.x * blockDim.x + threadIdx.x;
    int wave = tid >> 6;
    int lane = tid & 63;
    int slot = wave * NPW + lane / L;
    if (slot >= n) return;
    int node = order[slot];
    int sub = lane % L;
    int f = sub * VEC;

    float xrv[8], attv[8], acc[8];
    {
        const float4* xrp = (const float4*)(xr + (size_t)node * HD + f);
        float4 a0 = xrp[0], a1 = xrp[1];
        xrv[0]=a0.x; xrv[1]=a0.y; xrv[2]=a0.z; xrv[3]=a0.w;
        xrv[4]=a1.x; xrv[5]=a1.y; xrv[6]=a1.z; xrv[7]=a1.w;
        const float4* ap = (const float4*)(att + f);
        float4 t0 = ap[0], t1 = ap[1];
        attv[0]=t0.x; attv[1]=t0.y; attv[2]=t0.z; attv[3]=t0.w;
        attv[4]=t1.x; attv[5]=t1.y; attv[6]=t1.z; attv[7]=t1.w;
#pragma unroll
        for (int i = 0; i < 8; i++) acc[i] = 0.f;
    }
    int e0 = rowptr[node];
    int deg = rowptr[node + 1] - e0;
    float m = -INFINITY, denom = 0.f;
    // 1-deep software pipeline on the gather
    int s = csr_src[e0];
    const float4* xp = (const float4*)(xl + (size_t)s * HD + f);
    float4 u0 = xp[0], u1 = xp[1];
    for (int j = 0; j < deg; j++) {
        float4 c0 = u0, c1 = u1;
        if (j + 1 < deg) {
            int s2 = csr_src[e0 + j + 1];
            const float4* xp2 = (const float4*)(xl + (size_t)s2 * HD + f);
            u0 = xp2[0]; u1 = xp2[1];
        }
        float xlv[8] = {c0.x, c0.y, c0.z, c0.w, c1.x, c1.y, c1.z, c1.w};
        float part = 0.f;
#pragma unroll
        for (int i = 0; i < 8; i++) {
            float e = xlv[i] + xrv[i];
            e = (e > 0.f) ? e : 0.2f * e;
            part = fmaf(e, attv[i], part);
        }
#pragma unroll
        for (int msk = G / 2; msk >= 1; msk >>= 1) part += __shfl_xor(part, msk, 64);
        float nm = fmaxf(m, part);
        float sc = __expf(m - nm);
        float w  = __expf(part - nm);
        denom = fmaf(denom, sc, w);
#pragma unroll
        for (int i = 0; i < 8; i++) acc[i] = fmaf(acc[i], sc, w * xlv[i]);
        m = nm;
    }
    float inv = 1.f / denom;
    // ---- +bo, LayerNorm over HD dims (L lanes), ELU ----
    float v[8];
    float s1 = 0.f;
#pragma unroll
    for (int i = 0; i < 8; i++) {
        v[i] = acc[i] * inv + bo[f + i];
        s1 += v[i];
    }
#pragma unroll
    for (int msk = L / 2; msk >= 1; msk >>= 1) s1 += __shfl_xor(s1, msk, 64);
    float mu = s1 * (1.f / HD);
    float q = 0.f;
#pragma unroll
    for (int i = 0; i < 8; i++) { float d = v[i] - mu; q += d * d; }
#pragma unroll
    for (int msk = L / 2; msk >= 1; msk >>= 1) q += __shfl_xor(q, msk, 64);
    float rstd = rsqrtf(q * (1.f / HD) + 1e-5f);
    float y[8];
#pragma unroll
    for (int i = 0; i < 8; i++) {
        float t = (v[i] - mu) * rstd * g[f + i] + be[f + i];
        t = (t > 0.f) ? t : expm1f(t);
        if (RES) t += res[(size_t)node * HD + f + i];
        y[i] = t;
    }
    if constexpr (!CLS) {
        float4 o0 = {y[0], y[1], y[2], y[3]};
        float4 o1 = {y[4], y[5], y[6], y[7]};
        float4* op = (float4*)(outh + (size_t)node * HD + f);
        op[0] = o0; op[1] = o1;
    } else {
        // fused classifier: out[node] = w2 . ELU(y@W1 + b1) + b2  (HD==32, L==4)
        float pj[16];
#pragma unroll
        for (int j = 0; j < 16; j++) pj[j] = 0.f;
#pragma unroll
        for (int k = 0; k < 8; k++) {
#pragma unroll
            for (int j = 0; j < 16; j++)
                pj[j] = fmaf(y[k], w1s[(f + k) * 16 + j], pj[j]);
        }
#pragma unroll
        for (int j = 0; j < 16; j++) {
            pj[j] += __shfl_xor(pj[j], 1, 64);
            pj[j] += __shfl_xor(pj[j], 2, 64);
        }
        float o = b2s[0];
#pragma unroll
        for (int j = 0; j < 16; j++) {
            float a2 = pj[j] + b1s[j];
            a2 = (a2 > 0.f) ? a2 : expm1f(a2);
            o = fmaf(a2, w2s[j], o);
        }
        if (sub == 0) out[node] = o;
    }
}

// ---------------- launch ----------------

extern "C" void kernel_launch(void* const* d_in, const int* in_sizes, int n_in,
                              void* d_out, int out_size, void* d_ws, size_t ws_size,
                              hipStream_t stream) {
    (void)in_sizes; (void)n_in; (void)out_size; (void)ws_size;
    const float* x  = (const float*)d_in[0];
    const int*   ei = (const int*)d_in[1];
    const int* src = ei;
    const int* dst = ei + N_EDGES;

    const float* Wl0 = (const float*)d_in[2];
    const float* bl0 = (const float*)d_in[3];
    const float* Wr0 = (const float*)d_in[4];
    const float* br0 = (const float*)d_in[5];
    const float* att0= (const float*)d_in[6];
    const float* bo0 = (const float*)d_in[7];
    const float* g0  = (const float*)d_in[8];
    const float* be0 = (const float*)d_in[9];
    const float* Wl1 = (const float*)d_in[10];
    const float* bl1 = (const float*)d_in[11];
    const float* Wr1 = (const float*)d_in[12];
    const float* br1 = (const float*)d_in[13];
    const float* att1= (const float*)d_in[14];
    const float* bo1 = (const float*)d_in[15];
    const float* g1  = (const float*)d_in[16];
    const float* be1 = (const float*)d_in[17];
    const float* Wl2 = (const float*)d_in[18];
    const float* bl2 = (const float*)d_in[19];
    const float* Wr2 = (const float*)d_in[20];
    const float* br2 = (const float*)d_in[21];
    const float* att2= (const float*)d_in[22];
    const float* bo2 = (const float*)d_in[23];
    const float* g2  = (const float*)d_in[24];
    const float* be2 = (const float*)d_in[25];
    const float* cW1 = (const float*)d_in[26];
    const float* cb1 = (const float*)d_in[27];
    const float* cW2 = (const float*)d_in[28];
    const float* cb2 = (const float*)d_in[29];

    char* ws = (char*)d_ws;
    float* xl = (float*)ws; ws += (size_t)N_NODES * 128 * 4;
    float* xr = (float*)ws; ws += (size_t)N_NODES * 128 * 4;
    float* h0 = (float*)ws; ws += (size_t)N_NODES * 128 * 4;
    float* h1 = (float*)ws; ws += (size_t)N_NODES * 128 * 4;
    int* rowptr  = (int*)ws; ws += (size_t)(N_NODES + 1) * 4;
    int* cursor  = (int*)ws; ws += (size_t)N_NODES * 4;
    int* deg     = (int*)ws; ws += (size_t)N_NODES * 4;
    int* csr_src = (int*)ws; ws += (size_t)ET * 4;
    int* hist    = (int*)ws; ws += 256 * 4;
    int* bincur  = (int*)ws; ws += 256 * 4;
    int* order   = (int*)ws; ws += (size_t)N_NODES * 4;

    // ---- CSR build ----
    k_init_deg<<<(N_NODES + 255) / 256, 256, 0, stream>>>(deg, N_NODES);
    k_count<<<(N_EDGES + 255) / 256, 256, 0, stream>>>(dst, deg, N_EDGES);
    k_scan<<<1, 1024, 0, stream>>>(deg, rowptr, cursor, N_NODES);
    k_fill<<<(ET + 255) / 256, 256, 0, stream>>>(src, dst, cursor, csr_src);
    // ---- degree sort ----
    k_zero256<<<1, 256, 0, stream>>>(hist);
    k_hist<<<64, 256, 0, stream>>>(deg, hist, N_NODES);
    k_binstart<<<1, 256, 0, stream>>>(hist, bincur);
    k_scatter<<<(N_NODES + 255) / 256, 256, 0, stream>>>(deg, bincur, order, N_NODES);

    const int gx128 = (N_NODES + 127) / 128;    // 391 M-tiles (BM=128)
    const int gridG128 = (N_NODES + 15) / 16;   // 16 nodes/block (VEC=8, HD=128)
    const int gridG32  = (N_NODES + 63) / 64;   // 64 nodes/block (VEC=8, HD=32)

    // ---- layer 0: K=18 -> 4x32 concat=128 ----
    k_gemm_t<18, 18, 128, 128, 8, 8><<<dim3(gx128, 2), 256, 0, stream>>>(
        x, Wl0, bl0, Wr0, br0, xl, xr, N_NODES);
    k_gather_ln<128, 32, false, false><<<gridG128, 256, 0, stream>>>(
        xl, xr, att0, rowptr, csr_src, order, bo0, g0, be0, nullptr, h0,
        nullptr, nullptr, nullptr, nullptr, nullptr, N_NODES);

    // ---- layer 1: K=128 -> 4x32 concat=128, residual ----
    k_gemm_t<128, 32, 128, 128, 8, 8><<<dim3(gx128, 2), 256, 0, stream>>>(
        h0, Wl1, bl1, Wr1, br1, xl, xr, N_NODES);
    k_gather_ln<128, 32, true, false><<<gridG128, 256, 0, stream>>>(
        xl, xr, att1, rowptr, csr_src, order, bo1, g1, be1, h0, h1,
        nullptr, nullptr, nullptr, nullptr, nullptr, N_NODES);

    // ---- layer 2: K=128 -> 1x32 + fused classifier ----
    k_gemm_t<128, 32, 32, 32, 8, 2><<<dim3(gx128, 2), 256, 0, stream>>>(
        h1, Wl2, bl2, Wr2, br2, xl, xr, N_NODES);
    k_gather_ln<32, 32, false, true><<<gridG32, 256, 0, stream>>>(
        xl, xr, att2, rowptr, csr_src, order, bo2, g2, be2, nullptr, nullptr,
        cW1, cb1, cW2, cb2, (float*)d_out, N_NODES);
}